// Round 1
// baseline (349.867 us; speedup 1.0000x reference)
//
#include <hip/hip_runtime.h>
#include <hip/hip_bf16.h>
#include <stdint.h>

#define DEVI __device__ __forceinline__

typedef __attribute__((ext_vector_type(8))) short bf16x8;
typedef __attribute__((ext_vector_type(4))) float f32x4;

DEVI float bf2f(short u) {
  union { unsigned int i; float f; } v;
  v.i = ((unsigned int)(unsigned short)u) << 16;
  return v.f;
}
DEVI short f2bf(float f) {
  union { float f; unsigned int i; } v; v.f = f;
  unsigned int r = v.i + 0x7FFFu + ((v.i >> 16) & 1u);  // RNE
  return (short)(r >> 16);
}

// LDS tile: row stride 64 shorts (128B), 16B-chunk XOR swizzle by (row&7).
// k0 must be a multiple of 8.
DEVI bf16x8 ldsfrag(const short* t, int row, int k0) {
  int slot = k0 >> 3;
  return *(const bf16x8*)(t + row * 64 + ((slot ^ (row & 7)) << 3));
}

// ---------------- fp32 -> bf16 convert (vectorized) ----------------
__global__ void k_cvt(const float* __restrict__ in, short* __restrict__ out, int n4) {
  int i = blockIdx.x * blockDim.x + threadIdx.x;
  if (i >= n4) return;
  float4 v = ((const float4*)in)[i];
  short4 o;
  o.x = f2bf(v.x); o.y = f2bf(v.y); o.z = f2bf(v.z); o.w = f2bf(v.w);
  ((short4*)out)[i] = o;
}

// ---------------- transpose + convert: in (R x C) f32 -> out (C x R) bf16 ----------------
__global__ void k_transpose_bf16(const float* __restrict__ in, short* __restrict__ outp,
                                 int R, int C) {
  __shared__ float tile[32][33];
  const int c0 = blockIdx.x * 32, r0 = blockIdx.y * 32;
  const int tx = threadIdx.x, ty = threadIdx.y;
  for (int i = ty; i < 32; i += 8) tile[i][tx] = in[(size_t)(r0 + i) * C + c0 + tx];
  __syncthreads();
  for (int i = ty; i < 32; i += 8) outp[(size_t)(c0 + i) * R + r0 + tx] = f2bf(tile[tx][i]);
}

// ---------------- RoPE tables: cos/sin[s][i], s<2048, i<32 ----------------
__global__ void k_rope(float* __restrict__ cosT, float* __restrict__ sinT) {
  int idx = blockIdx.x * blockDim.x + threadIdx.x;  // 2048*32
  int s = idx >> 5, i = idx & 31;
  // inv_freq = 10000^(-i/32) = exp2(-i * log2(10000)/32)
  float inv = exp2f(-0.41524101186092034f * (float)i);
  float freq = (float)s * inv;
  cosT[idx] = cosf(freq);
  sinT[idx] = sinf(freq);
}

// ---------------- bf16 MFMA GEMM: C(MxN) = A(MxK) * BT(NxK)^T + bias ----------------
// BM=BN=128, BK=64, 256 threads (4 waves, 2x2), each wave 64x64.
template <int OUTF32>
__global__ __launch_bounds__(256) void k_gemm(const short* __restrict__ A,
                                              const short* __restrict__ BT,
                                              const float* __restrict__ bias,
                                              void* __restrict__ outp,
                                              int M, int N, int K) {
  __shared__ __align__(16) short As[128 * 64];
  __shared__ __align__(16) short Bs[128 * 64];
  const int tid = threadIdx.x;
  const int lane = tid & 63, wid = tid >> 6;
  const int ln = lane & 15, grp = lane >> 4;
  const int wm = wid >> 1, wn = wid & 1;
  const int r0 = blockIdx.y * 128, c0 = blockIdx.x * 128;

  f32x4 acc[4][4];
#pragma unroll
  for (int i = 0; i < 4; ++i)
#pragma unroll
    for (int j = 0; j < 4; ++j) acc[i][j] = (f32x4){0.f, 0.f, 0.f, 0.f};

  const int nkt = K >> 6;
  for (int kt = 0; kt < nkt; ++kt) {
    __syncthreads();
#pragma unroll
    for (int i = 0; i < 4; ++i) {
      int c = tid + i * 256;          // 1024 16B-chunks per tile
      int row = c >> 3, slot = c & 7;
      int sw = row * 64 + ((slot ^ (row & 7)) << 3);
      *(int4*)(&As[sw]) = *(const int4*)(A + (size_t)(r0 + row) * K + (size_t)kt * 64 + slot * 8);
      *(int4*)(&Bs[sw]) = *(const int4*)(BT + (size_t)(c0 + row) * K + (size_t)kt * 64 + slot * 8);
    }
    __syncthreads();
#pragma unroll
    for (int ks = 0; ks < 2; ++ks) {
      const int k0 = ks * 32 + grp * 8;
      bf16x8 af[4], bfr[4];
#pragma unroll
      for (int mi = 0; mi < 4; ++mi) af[mi] = ldsfrag(As, wm * 64 + mi * 16 + ln, k0);
#pragma unroll
      for (int ni = 0; ni < 4; ++ni) bfr[ni] = ldsfrag(Bs, wn * 64 + ni * 16 + ln, k0);
#pragma unroll
      for (int mi = 0; mi < 4; ++mi)
#pragma unroll
        for (int ni = 0; ni < 4; ++ni)
          acc[mi][ni] = __builtin_amdgcn_mfma_f32_16x16x32_bf16(af[mi], bfr[ni], acc[mi][ni], 0, 0, 0);
    }
  }
#pragma unroll
  for (int ni = 0; ni < 4; ++ni) {
    const int col = c0 + wn * 64 + ni * 16 + ln;
    const float bv = bias[col];
#pragma unroll
    for (int mi = 0; mi < 4; ++mi) {
#pragma unroll
      for (int r = 0; r < 4; ++r) {
        const int rowg = r0 + wm * 64 + mi * 16 + grp * 4 + r;
        float v = acc[mi][ni][r] + bv;
        if (OUTF32) ((float*)outp)[(size_t)rowg * N + col] = v;
        else        ((short*)outp)[(size_t)rowg * N + col] = f2bf(v);
      }
    }
  }
}

// ---------------- qkv (8192x3072 bf16) -> q (roped, *0.125), k (roped), v^T ----------------
// q,k: (bh, s, d) bf16; vT: (bh, d, s) bf16. block = (s-tile 64, bh), 256 thr.
__global__ __launch_bounds__(256) void k_transform(const short* __restrict__ qkv,
                                                   const float* __restrict__ cosT,
                                                   const float* __restrict__ sinT,
                                                   short* __restrict__ qo,
                                                   short* __restrict__ ko,
                                                   short* __restrict__ vT) {
  __shared__ __align__(16) short vs[64 * 72];
  const int st = blockIdx.x, bh = blockIdx.y;
  const int b = bh >> 4, h = bh & 15;
  const int t = threadIdx.x;
  {
    const int sl = t >> 2, j = t & 3;
    const int s = st * 64 + sl;
    const short* row = qkv + ((size_t)(b * 2048 + s)) * 3072 + h * 64;
    bf16x8 qlo = *(const bf16x8*)(row + j * 8);
    bf16x8 qhi = *(const bf16x8*)(row + 32 + j * 8);
    bf16x8 klo = *(const bf16x8*)(row + 1024 + j * 8);
    bf16x8 khi = *(const bf16x8*)(row + 1056 + j * 8);
    const float* cp = cosT + s * 32 + j * 8;
    const float* sp = sinT + s * 32 + j * 8;
    bf16x8 ql, qh, kl, kh;
#pragma unroll
    for (int e = 0; e < 8; ++e) {
      float c = cp[e], sn = sp[e];
      float a1 = bf2f(qlo[e]), a2 = bf2f(qhi[e]);
      ql[e] = f2bf((a1 * c - a2 * sn) * 0.125f);
      qh[e] = f2bf((a1 * sn + a2 * c) * 0.125f);
      float b1 = bf2f(klo[e]), b2 = bf2f(khi[e]);
      kl[e] = f2bf(b1 * c - b2 * sn);
      kh[e] = f2bf(b1 * sn + b2 * c);
    }
    short* qrow = qo + ((size_t)bh * 2048 + s) * 64;
    short* krow = ko + ((size_t)bh * 2048 + s) * 64;
    *(bf16x8*)(qrow + j * 8) = ql;
    *(bf16x8*)(qrow + 32 + j * 8) = qh;
    *(bf16x8*)(krow + j * 8) = kl;
    *(bf16x8*)(krow + 32 + j * 8) = kh;
    // stage v tile for transpose
    bf16x8 v0 = *(const bf16x8*)(row + 2048 + j * 16);
    bf16x8 v1 = *(const bf16x8*)(row + 2048 + j * 16 + 8);
    *(bf16x8*)(&vs[sl * 72 + j * 16]) = v0;
    *(bf16x8*)(&vs[sl * 72 + j * 16 + 8]) = v1;
  }
  __syncthreads();
  {
    const int d = t >> 2, sc = (t & 3) * 16;
    bf16x8 o0, o1;
#pragma unroll
    for (int i = 0; i < 8; ++i) o0[i] = vs[(sc + i) * 72 + d];
#pragma unroll
    for (int i = 0; i < 8; ++i) o1[i] = vs[(sc + 8 + i) * 72 + d];
    short* vrow = vT + (size_t)bh * 64 * 2048 + (size_t)d * 2048 + st * 64 + sc;
    *(bf16x8*)(vrow) = o0;
    *(bf16x8*)(vrow + 8) = o1;
  }
}

// ---------------- flash attention ----------------
// grid (qt=32, bh=64), 256 thr = 4 waves; QBLK=KVBLK=64, HD=64.
// q pre-scaled by 1/8. out: (b*2048+s, h*64+d) bf16.
__global__ __launch_bounds__(256) void k_attn(const short* __restrict__ Q,
                                              const short* __restrict__ Kk,
                                              const short* __restrict__ VT,
                                              short* __restrict__ out) {
  __shared__ __align__(16) short Qs[64 * 64];
  __shared__ __align__(16) short Ks[64 * 64];
  __shared__ __align__(16) short Vs[64 * 64];   // [d][key] (V^T tile)
  __shared__ __align__(16) short Ps[4 * 16 * 64];
  const int tid = threadIdx.x;
  const int lane = tid & 63, wid = tid >> 6;
  const int ln = lane & 15, grp = lane >> 4;
  const int qt = blockIdx.x, bh = blockIdx.y;
  const int b = bh >> 4, h = bh & 15;

  const short* qbase = Q + ((size_t)bh * 2048 + qt * 64) * 64;
#pragma unroll
  for (int i = 0; i < 2; ++i) {
    int c = tid + i * 256;
    int row = c >> 3, slot = c & 7;
    *(int4*)(&Qs[row * 64 + ((slot ^ (row & 7)) << 3)]) =
        *(const int4*)(qbase + row * 64 + slot * 8);
  }
  __syncthreads();
  bf16x8 qf[2];
  qf[0] = ldsfrag(Qs, wid * 16 + ln, grp * 8);
  qf[1] = ldsfrag(Qs, wid * 16 + ln, 32 + grp * 8);

  f32x4 acc[4];
  float m[4], l[4];
#pragma unroll
  for (int i = 0; i < 4; ++i) { acc[i] = (f32x4){0.f, 0.f, 0.f, 0.f}; m[i] = -1e30f; l[i] = 0.f; }

  const short* kbase = Kk + (size_t)bh * 2048 * 64;
  const short* vbase = VT + (size_t)bh * 64 * 2048;

  for (int t = 0; t < 32; ++t) {
    __syncthreads();
#pragma unroll
    for (int i = 0; i < 2; ++i) {
      int c = tid + i * 256;
      int row = c >> 3, slot = c & 7;
      int sw = row * 64 + ((slot ^ (row & 7)) << 3);
      *(int4*)(&Ks[sw]) = *(const int4*)(kbase + (size_t)(t * 64 + row) * 64 + slot * 8);
      *(int4*)(&Vs[sw]) = *(const int4*)(vbase + (size_t)row * 2048 + t * 64 + slot * 8);
    }
    __syncthreads();

    // S = Q K^T  (q pre-scaled)
    f32x4 sf[4];
#pragma unroll
    for (int ni = 0; ni < 4; ++ni) sf[ni] = (f32x4){0.f, 0.f, 0.f, 0.f};
#pragma unroll
    for (int ks = 0; ks < 2; ++ks) {
      const int k0 = ks * 32 + grp * 8;
      bf16x8 qv = qf[ks];
#pragma unroll
      for (int ni = 0; ni < 4; ++ni) {
        bf16x8 kf = ldsfrag(Ks, ni * 16 + ln, k0);
        sf[ni] = __builtin_amdgcn_mfma_f32_16x16x32_bf16(qv, kf, sf[ni], 0, 0, 0);
      }
    }

    // online softmax (rows live across the 16 lanes of each lane-group)
    float mx[4];
#pragma unroll
    for (int r = 0; r < 4; ++r)
      mx[r] = fmaxf(fmaxf(sf[0][r], sf[1][r]), fmaxf(sf[2][r], sf[3][r]));
#pragma unroll
    for (int off = 1; off < 16; off <<= 1)
#pragma unroll
      for (int r = 0; r < 4; ++r) mx[r] = fmaxf(mx[r], __shfl_xor(mx[r], off));
    float al[4], ps[4];
#pragma unroll
    for (int r = 0; r < 4; ++r) {
      float mn = fmaxf(m[r], mx[r]);
      al[r] = __expf(m[r] - mn);
      m[r] = mn;
      ps[r] = 0.f;
    }
#pragma unroll
    for (int ni = 0; ni < 4; ++ni)
#pragma unroll
      for (int r = 0; r < 4; ++r) {
        float pv = __expf(sf[ni][r] - m[r]);
        sf[ni][r] = pv;
        ps[r] += pv;
      }
#pragma unroll
    for (int off = 1; off < 16; off <<= 1)
#pragma unroll
      for (int r = 0; r < 4; ++r) ps[r] += __shfl_xor(ps[r], off);
#pragma unroll
    for (int r = 0; r < 4; ++r) l[r] = l[r] * al[r] + ps[r];
#pragma unroll
    for (int ni = 0; ni < 4; ++ni) {
      f32x4 a = acc[ni];
#pragma unroll
      for (int r = 0; r < 4; ++r) a[r] *= al[r];
      acc[ni] = a;
    }

    // P -> per-wave LDS (true coords, swizzled)
    short* pw = Ps + wid * 1024;
#pragma unroll
    for (int ni = 0; ni < 4; ++ni)
#pragma unroll
      for (int r = 0; r < 4; ++r) {
        int rp = grp * 4 + r, colp = ni * 16 + ln;
        pw[rp * 64 + (colp ^ ((rp & 7) << 3))] = f2bf(sf[ni][r]);
      }
    __syncthreads();

    // O += P V
#pragma unroll
    for (int ks = 0; ks < 2; ++ks) {
      const int k0 = ks * 32 + grp * 8;
      bf16x8 pa = ldsfrag(pw, ln, k0);
#pragma unroll
      for (int ni = 0; ni < 4; ++ni) {
        bf16x8 vf = ldsfrag(Vs, ni * 16 + ln, k0);
        acc[ni] = __builtin_amdgcn_mfma_f32_16x16x32_bf16(pa, vf, acc[ni], 0, 0, 0);
      }
    }
  }

#pragma unroll
  for (int ni = 0; ni < 4; ++ni)
#pragma unroll
    for (int r = 0; r < 4; ++r) {
      int srow = qt * 64 + wid * 16 + grp * 4 + r;
      float o = acc[ni][r] / l[r];
      out[((size_t)b * 2048 + srow) * 1024 + h * 64 + ni * 16 + ln] = f2bf(o);
    }
}

extern "C" void kernel_launch(void* const* d_in, const int* in_sizes, int n_in,
                              void* d_out, int out_size, void* d_ws, size_t ws_size,
                              hipStream_t stream) {
  const float* x    = (const float*)d_in[0];  // (4,2048,1024)
  const float* Wqkv = (const float*)d_in[1];  // (1024,3072)
  const float* bqkv = (const float*)d_in[2];  // (3072,)
  const float* Wout = (const float*)d_in[3];  // (1024,1024)
  const float* bout = (const float*)d_in[4];  // (1024,)
  float* out = (float*)d_out;                 // (8192,1024) f32

  // workspace layout (~137 MiB total)
  char* p = (char*)d_ws;
  short* xb    = (short*)p; p += (size_t)8192 * 1024 * 2;
  short* wqkvT = (short*)p; p += (size_t)3072 * 1024 * 2;
  short* woutT = (short*)p; p += (size_t)1024 * 1024 * 2;
  float* cosT  = (float*)p; p += (size_t)2048 * 32 * 4;
  float* sinT  = (float*)p; p += (size_t)2048 * 32 * 4;
  short* qkvb  = (short*)p; p += (size_t)8192 * 3072 * 2;
  short* qb    = (short*)p; p += (size_t)64 * 2048 * 64 * 2;
  short* kb    = (short*)p; p += (size_t)64 * 2048 * 64 * 2;
  short* vTb   = (short*)p; p += (size_t)64 * 2048 * 64 * 2;
  short* ao    = (short*)p; p += (size_t)8192 * 1024 * 2;

  k_cvt<<<8192 * 1024 / 4 / 256, 256, 0, stream>>>(x, xb, 8192 * 1024 / 4);
  k_transpose_bf16<<<dim3(3072 / 32, 1024 / 32), dim3(32, 8), 0, stream>>>(Wqkv, wqkvT, 1024, 3072);
  k_transpose_bf16<<<dim3(1024 / 32, 1024 / 32), dim3(32, 8), 0, stream>>>(Wout, woutT, 1024, 1024);
  k_rope<<<2048 * 32 / 256, 256, 0, stream>>>(cosT, sinT);
  k_gemm<0><<<dim3(3072 / 128, 8192 / 128), 256, 0, stream>>>(xb, wqkvT, bqkv, (void*)qkvb,
                                                              8192, 3072, 1024);
  k_transform<<<dim3(32, 64), 256, 0, stream>>>(qkvb, cosT, sinT, qb, kb, vTb);
  k_attn<<<dim3(32, 64), 256, 0, stream>>>(qb, kb, vTb, ao);
  k_gemm<1><<<dim3(1024 / 128, 8192 / 128), 256, 0, stream>>>(ao, woutT, bout, (void*)out,
                                                              8192, 1024, 1024);
}